// Round 1
// baseline (9301.322 us; speedup 1.0000x reference)
//
#include <hip/hip_runtime.h>
#include <float.h>
#include <stdint.h>

#define QB        16
#define NTHREADS  512
#define LQ        2048
#define NDIM      64
#define KSEL      128
#define LDS_BYTES 159808

// Order-preserving map fp32 -> uint32 (monotone increasing)
__device__ __forceinline__ unsigned ordf(float f) {
  unsigned u = __float_as_uint(f);
  return (u & 0x80000000u) ? ~u : (u | 0x80000000u);
}
__device__ __forceinline__ float unordf(unsigned u) {
  unsigned x = (u & 0x80000000u) ? (u & 0x7FFFFFFFu) : ~u;
  return __uint_as_float(x);
}

extern "C" __global__ void __launch_bounds__(NTHREADS, 2)
topk_attn(const float* __restrict__ Qg_, const float* __restrict__ Kg_,
          const float* __restrict__ Vg_, float* __restrict__ Out) {
  extern __shared__ char lds[];
  float*    s_phys = (float*)(lds);              // [QB][LQ]   131072 B
  float*    qs     = (float*)(lds + 131072);     // [QB][NDIM]   4096 B
  unsigned* hist   = (unsigned*)(lds + 135168);  // [8][256]     8192 B
  int*      lists  = (int*)(lds + 143360);       // [QB][KSEL]   8192 B
  float*    wlist  = (float*)(lds + 151552);     // [QB][KSEL]   8192 B
  int*      llen   = (int*)(lds + 159744);       // [QB]           64 B

  const int bh   = blockIdx.y;
  const int q0   = blockIdx.x * QB;
  const int tid  = threadIdx.x;
  const int lane = tid & 63;
  const int wid  = tid >> 6;

  const float* Qg = Qg_ + ((size_t)(bh * LQ + q0)) * NDIM;
  const float* Kg = Kg_ + ((size_t)bh) * LQ * NDIM;
  const float* Vg = Vg_ + ((size_t)bh) * LQ * NDIM;

  // ---- stage Q block into LDS (coalesced float4) ----
  if (tid < QB * NDIM / 4) ((float4*)qs)[tid] = ((const float4*)Qg)[tid];
  __syncthreads();

  // ---- QK^T: 8q x 8k register microtile per thread ----
  const int tq   = tid >> 8;      // 0..1  (query group of 8)
  const int tk   = tid & 255;     // 0..255 (key group of 8)
  const int j0   = tk << 3;
  const int qmax = q0 + QB - 1;
  const bool active = (j0 <= qmax);

  float acc[8][8];
#pragma unroll
  for (int i = 0; i < 8; ++i)
#pragma unroll
    for (int j = 0; j < 8; ++j) acc[i][j] = 0.f;

  if (active) {
    const float4* K4  = (const float4*)(Kg + (size_t)j0 * NDIM); // row r: K4[r*16 + d4]
    const float4* qs4 = (const float4*)(qs + tq * 8 * NDIM);     // q row i: qs4[i*16 + d4]
#pragma unroll
    for (int h = 0; h < 2; ++h) {          // two 4-row halves of the 8 keys
#pragma unroll
      for (int d16 = 0; d16 < 4; ++d16) {  // 16-dim chunks (64B contiguous per row)
        float4 kv[4][4];
#pragma unroll
        for (int r = 0; r < 4; ++r)
#pragma unroll
          for (int c = 0; c < 4; ++c)
            kv[r][c] = K4[(h * 4 + r) * 16 + d16 * 4 + c];
#pragma unroll
        for (int c = 0; c < 4; ++c) {
          float4 qv[8];
#pragma unroll
          for (int i = 0; i < 8; ++i) qv[i] = qs4[i * 16 + d16 * 4 + c];
#pragma unroll
          for (int i = 0; i < 8; ++i)
#pragma unroll
            for (int r = 0; r < 4; ++r) {
              acc[i][h * 4 + r] += qv[i].x * kv[r][c].x + qv[i].y * kv[r][c].y +
                                   qv[i].z * kv[r][c].z + qv[i].w * kv[r][c].w;
            }
        }
      }
    }
  }

  // ---- write scores to LDS in transposed phys layout: p = tk + jj*256 (conflict-free) ----
#pragma unroll
  for (int i = 0; i < 8; ++i) {
    const int q = q0 + tq * 8 + i;
    float* srow = s_phys + (tq * 8 + i) * LQ;
#pragma unroll
    for (int jj = 0; jj < 8; ++jj) {
      const int j = j0 + jj;
      srow[tk + jj * 256] = (active && j <= q) ? acc[i][jj] : -FLT_MAX;
    }
  }
  __syncthreads();

  // ---- per-wave: exact top-128 radix select + softmax + PV gather ----
  unsigned* myhist = hist + wid * 256;
  const float C = 0.18033688011112042f; // 0.125 * log2(e)

  for (int qi = wid; qi < QB; qi += 8) {
    const int q = q0 + qi;
    const float* srow = s_phys + qi * LQ;

    // 4-round radix select: find 128th-largest value (ordered-uint space)
    unsigned prefix = 0;
    int k = KSEL;
    for (int round = 0; round < 4; ++round) {
      const int shift = 24 - 8 * round;
      *(uint4*)(&myhist[lane * 4]) = make_uint4(0u, 0u, 0u, 0u);
      __threadfence_block();
      const unsigned maskhi = (round == 0) ? 0u : (0xFFFFFFFFu << (shift + 8));
      for (int i = 0; i < 32; ++i) {
        const unsigned u = ordf(srow[lane + (i << 6)]);
        if ((u & maskhi) == prefix) atomicAdd(&myhist[(u >> shift) & 255], 1u);
      }
      __threadfence_block();
      uint4 hv4 = *(uint4*)(&myhist[lane * 4]);
      unsigned hb[4] = {hv4.x, hv4.y, hv4.z, hv4.w};
      const unsigned g0 = hb[0] + hb[1] + hb[2] + hb[3];
      unsigned gs = g0;
#pragma unroll
      for (int off = 1; off < 64; off <<= 1) {
        const unsigned o = __shfl_down(gs, off, 64);
        if (lane + off < 64) gs += o;
      }
      const unsigned sexcl = gs - g0;
      const bool cross = (sexcl < (unsigned)k) && (sexcl + g0 >= (unsigned)k);
      unsigned long long bal = __ballot(cross);
      int lsel = (bal == 0ull) ? 0 : (__ffsll((unsigned long long)bal) - 1);
      int bstar = 0, knew = k;
      if (cross) {
        unsigned cum = sexcl;
#pragma unroll
        for (int bb = 3; bb >= 0; --bb) {
          const unsigned hv = hb[bb];
          if (cum + hv >= (unsigned)k) { bstar = lane * 4 + bb; knew = k - (int)cum; break; }
          cum += hv;
        }
      }
      bstar = __shfl(bstar, lsel, 64);
      knew  = __shfl(knew, lsel, 64);
      prefix |= ((unsigned)bstar) << shift;
      k = knew;
    }
    const unsigned tu = prefix;      // exact threshold (ordered)
    const int krem = k;              // how many == tu belong in the top-128
    const float tf = unordf(tu);
    const float wt = exp2f(tf * C);  // 0 for -FLT_MAX threshold (q<127 rows)

    if (lane == 0) llen[qi] = 0;
    __threadfence_block();

    float zacc = 0.f;
    int myeq = 0;
    for (int i = 0; i < 32; ++i) {
      const int p = lane + (i << 6);
      const float f = srow[p];
      const unsigned u = ordf(f);
      if (u > tu) {
        const int pos = atomicAdd(&llen[qi], 1);
        if (pos < KSEL) {
          lists[qi * KSEL + pos] = ((p & 255) << 3) | (p >> 8);
          const float w = exp2f(f * C);
          wlist[qi * KSEL + pos] = w;
          zacc += w;
        }
      } else if (u == tu) {
        myeq++;
      }
    }
    if (wt > 0.f) {
      int te = myeq;
#pragma unroll
      for (int off = 1; off < 64; off <<= 1) te += __shfl_xor(te, off, 64);
      if (te == krem) {
        // common case: include every tied element
        for (int i = 0; i < 32; ++i) {
          const int p = lane + (i << 6);
          if (ordf(srow[p]) == tu) {
            const int pos = atomicAdd(&llen[qi], 1);
            if (pos < KSEL) {
              lists[qi * KSEL + pos] = ((p & 255) << 3) | (p >> 8);
              wlist[qi * KSEL + pos] = wt;
              zacc += wt;
            }
          }
        }
      } else {
        // rare: more ties than slots -> take smallest indices (reference tie order)
        if (lane == 0) {
          int taken = 0;
          for (int j = 0; j < LQ && taken < krem; ++j) {
            const int p = (j >> 3) + ((j & 7) << 8);
            if (ordf(srow[p]) == tu) {
              const int pos = llen[qi];
              llen[qi] = pos + 1;
              if (pos < KSEL) { lists[qi * KSEL + pos] = j; wlist[qi * KSEL + pos] = wt; }
              taken++;
            }
          }
          zacc += wt * (float)krem;
        }
      }
    }
    float Z = zacc;
#pragma unroll
    for (int off = 1; off < 64; off <<= 1) Z += __shfl_xor(Z, off, 64);
    __threadfence_block();
    int n = llen[qi];
    if (n > KSEL) n = KSEL;

    // ---- PV gather: lane = output dim ----
    float accv = 0.f;
    int i = 0;
    for (; i + 4 <= n; i += 4) {
      const int ja = lists[qi * KSEL + i + 0];
      const int jb = lists[qi * KSEL + i + 1];
      const int jc = lists[qi * KSEL + i + 2];
      const int jd = lists[qi * KSEL + i + 3];
      const float wa = wlist[qi * KSEL + i + 0];
      const float wb = wlist[qi * KSEL + i + 1];
      const float wc = wlist[qi * KSEL + i + 2];
      const float wd = wlist[qi * KSEL + i + 3];
      const float va = Vg[(size_t)ja * NDIM + lane];
      const float vb = Vg[(size_t)jb * NDIM + lane];
      const float vc = Vg[(size_t)jc * NDIM + lane];
      const float vd = Vg[(size_t)jd * NDIM + lane];
      accv += wa * va + wb * vb + wc * vc + wd * vd;
    }
    for (; i < n; ++i) {
      const int j = lists[qi * KSEL + i];
      accv += wlist[qi * KSEL + i] * Vg[(size_t)j * NDIM + lane];
    }
    Out[((size_t)(bh * LQ + q)) * NDIM + lane] = accv / Z;
  }
}

extern "C" void kernel_launch(void* const* d_in, const int* in_sizes, int n_in,
                              void* d_out, int out_size, void* d_ws, size_t ws_size,
                              hipStream_t stream) {
  (void)in_sizes; (void)n_in; (void)d_ws; (void)ws_size; (void)out_size;
  const float* Q = (const float*)d_in[0];
  const float* K = (const float*)d_in[1];
  const float* V = (const float*)d_in[2];
  float* Out = (float*)d_out;

  // >64KB dynamic LDS needs the attribute on ROCm; idempotent, safe every call.
  (void)hipFuncSetAttribute(reinterpret_cast<const void*>(&topk_attn),
                            hipFuncAttributeMaxDynamicSharedMemorySize, LDS_BYTES);

  dim3 grid(LQ / QB, 64);  // 128 q-blocks x (B*H)
  topk_attn<<<grid, NTHREADS, LDS_BYTES, stream>>>(Q, K, V, Out);
}

// Round 2
// 3453.368 us; speedup vs baseline: 2.6934x; 2.6934x over previous
//
#include <hip/hip_runtime.h>
#include <float.h>
#include <stdint.h>

#define QB        16
#define NTHREADS  512
#define LQ        2048
#define NDIM      64
#define KSEL      128
#define LDS_BYTES 159808

// Order-preserving map fp32 -> uint32 (monotone increasing)
__device__ __forceinline__ unsigned ordf(float f) {
  unsigned u = __float_as_uint(f);
  return (u & 0x80000000u) ? ~u : (u | 0x80000000u);
}
__device__ __forceinline__ float unordf(unsigned u) {
  unsigned x = (u & 0x80000000u) ? (u & 0x7FFFFFFFu) : ~u;
  return __uint_as_float(x);
}

extern "C" __global__ void __launch_bounds__(NTHREADS, 2)
topk_attn(const float* __restrict__ Qg_, const float* __restrict__ Kg_,
          const float* __restrict__ Vg_, float* __restrict__ Out) {
  extern __shared__ char lds[];
  float*    s_phys = (float*)(lds);              // [QB][LQ]   131072 B
  float*    qs     = (float*)(lds + 131072);     // [QB][NDIM]   4096 B
  unsigned* hist   = (unsigned*)(lds + 135168);  // [8][256]     8192 B
  int*      lists  = (int*)(lds + 143360);       // [QB][KSEL]   8192 B
  float*    wlist  = (float*)(lds + 151552);     // [QB][KSEL]   8192 B
  int*      llen   = (int*)(lds + 159744);       // [QB]           64 B

  // ---- XCD-aware swizzle: 16 consecutive blocks per XCD share one (b,h) ----
  // HW round-robins linear block id over 8 XCDs: xcd = id & 7.
  const int id  = blockIdx.x;
  const int xcd = id & 7;
  const int w   = id >> 3;          // 0..1023
  const int bh  = w >> 4;           // 0..63  (16 consecutive w's share bh)
  const int qb  = ((w & 15) << 3) + xcd;  // 0..127, bijective with (bh,qb)

  const int q0   = qb * QB;
  const int tid  = threadIdx.x;
  const int lane = tid & 63;
  const int wid  = tid >> 6;

  const float* Qg = Qg_ + ((size_t)(bh * LQ + q0)) * NDIM;
  const float* Kg = Kg_ + ((size_t)bh) * LQ * NDIM;
  const float* Vg = Vg_ + ((size_t)bh) * LQ * NDIM;

  // ---- stage Q block into LDS (coalesced float4) ----
  if (tid < QB * NDIM / 4) ((float4*)qs)[tid] = ((const float4*)Qg)[tid];
  __syncthreads();

  // ---- QK^T: 8q x 8k register microtile per thread, spill-free ----
  const int tq   = tid >> 8;      // 0..1  (query group of 8)
  const int tk   = tid & 255;     // 0..255 (key group of 8)
  const int j0   = tk << 3;
  const int qmax = q0 + QB - 1;
  const bool active = (j0 <= qmax);

  float acc[8][8];
#pragma unroll
  for (int i = 0; i < 8; ++i)
#pragma unroll
    for (int j = 0; j < 8; ++j) acc[i][j] = 0.f;

  if (active) {
    const float4* K4  = (const float4*)(Kg + (size_t)j0 * NDIM); // row r: K4[r*16 + d4]
    const float4* qs4 = (const float4*)(qs + tq * 8 * NDIM);     // q row i: qs4[i*16 + d4]
#pragma unroll 1
    for (int d4 = 0; d4 < 16; ++d4) {
      float4 qv[8];
#pragma unroll
      for (int i = 0; i < 8; ++i) qv[i] = qs4[i * 16 + d4];
#pragma unroll
      for (int g = 0; g < 4; ++g) {
        const float4 k0 = K4[(2 * g + 0) * 16 + d4];
        const float4 k1 = K4[(2 * g + 1) * 16 + d4];
#pragma unroll
        for (int i = 0; i < 8; ++i) {
          acc[i][2 * g + 0] += qv[i].x * k0.x + qv[i].y * k0.y +
                               qv[i].z * k0.z + qv[i].w * k0.w;
          acc[i][2 * g + 1] += qv[i].x * k1.x + qv[i].y * k1.y +
                               qv[i].z * k1.z + qv[i].w * k1.w;
        }
      }
    }
  }

  // ---- write scores to LDS, transposed phys layout: p = tk + jj*256 (conflict-free) ----
#pragma unroll
  for (int i = 0; i < 8; ++i) {
    const int q = q0 + tq * 8 + i;
    float* srow = s_phys + (tq * 8 + i) * LQ;
#pragma unroll
    for (int jj = 0; jj < 8; ++jj) {
      const int j = j0 + jj;
      srow[tk + jj * 256] = (active && j <= q) ? acc[i][jj] : -FLT_MAX;
    }
  }
  __syncthreads();

  // ---- per-wave: exact top-128 radix select + softmax + PV gather ----
  unsigned* myhist = hist + wid * 256;
  const float C = 0.18033688011112042f; // 0.125 * log2(e)

  for (int qi = wid; qi < QB; qi += 8) {
    const int q = q0 + qi;
    const float* srow = s_phys + qi * LQ;

    // 4-round radix select: find 128th-largest value (ordered-uint space)
    unsigned prefix = 0;
    int k = KSEL;
    for (int round = 0; round < 4; ++round) {
      const int shift = 24 - 8 * round;
      *(uint4*)(&myhist[lane * 4]) = make_uint4(0u, 0u, 0u, 0u);
      __threadfence_block();
      const unsigned maskhi = (round == 0) ? 0u : (0xFFFFFFFFu << (shift + 8));
      for (int i = 0; i < 32; ++i) {
        const unsigned u = ordf(srow[lane + (i << 6)]);
        if ((u & maskhi) == prefix) atomicAdd(&myhist[(u >> shift) & 255], 1u);
      }
      __threadfence_block();
      uint4 hv4 = *(uint4*)(&myhist[lane * 4]);
      unsigned hb[4] = {hv4.x, hv4.y, hv4.z, hv4.w};
      const unsigned g0 = hb[0] + hb[1] + hb[2] + hb[3];
      unsigned gs = g0;
#pragma unroll
      for (int off = 1; off < 64; off <<= 1) {
        const unsigned o = __shfl_down(gs, off, 64);
        if (lane + off < 64) gs += o;
      }
      const unsigned sexcl = gs - g0;
      const bool cross = (sexcl < (unsigned)k) && (sexcl + g0 >= (unsigned)k);
      unsigned long long bal = __ballot(cross);
      int lsel = (bal == 0ull) ? 0 : (__ffsll((unsigned long long)bal) - 1);
      int bstar = 0, knew = k;
      if (cross) {
        unsigned cum = sexcl;
#pragma unroll
        for (int bb = 3; bb >= 0; --bb) {
          const unsigned hv = hb[bb];
          if (cum + hv >= (unsigned)k) { bstar = lane * 4 + bb; knew = k - (int)cum; break; }
          cum += hv;
        }
      }
      bstar = __shfl(bstar, lsel, 64);
      knew  = __shfl(knew, lsel, 64);
      prefix |= ((unsigned)bstar) << shift;
      k = knew;
    }
    const unsigned tu = prefix;      // exact threshold (ordered)
    const int krem = k;              // how many == tu belong in the top-128
    const float tf = unordf(tu);
    const float wt = exp2f(tf * C);  // 0 for -FLT_MAX threshold (q<127 rows)

    if (lane == 0) llen[qi] = 0;
    __threadfence_block();

    float zacc = 0.f;
    int myeq = 0;
    for (int i = 0; i < 32; ++i) {
      const int p = lane + (i << 6);
      const float f = srow[p];
      const unsigned u = ordf(f);
      if (u > tu) {
        const int pos = atomicAdd(&llen[qi], 1);
        if (pos < KSEL) {
          lists[qi * KSEL + pos] = ((p & 255) << 3) | (p >> 8);
          const float w = exp2f(f * C);
          wlist[qi * KSEL + pos] = w;
          zacc += w;
        }
      } else if (u == tu) {
        myeq++;
      }
    }
    if (wt > 0.f) {
      int te = myeq;
#pragma unroll
      for (int off = 1; off < 64; off <<= 1) te += __shfl_xor(te, off, 64);
      if (te == krem) {
        // common case: include every tied element
        for (int i = 0; i < 32; ++i) {
          const int p = lane + (i << 6);
          if (ordf(srow[p]) == tu) {
            const int pos = atomicAdd(&llen[qi], 1);
            if (pos < KSEL) {
              lists[qi * KSEL + pos] = ((p & 255) << 3) | (p >> 8);
              wlist[qi * KSEL + pos] = wt;
              zacc += wt;
            }
          }
        }
      } else {
        // rare: more ties than slots -> take smallest indices (reference tie order)
        if (lane == 0) {
          int taken = 0;
          for (int j = 0; j < LQ && taken < krem; ++j) {
            const int p = (j >> 3) + ((j & 7) << 8);
            if (ordf(srow[p]) == tu) {
              const int pos = llen[qi];
              llen[qi] = pos + 1;
              if (pos < KSEL) { lists[qi * KSEL + pos] = j; wlist[qi * KSEL + pos] = wt; }
              taken++;
            }
          }
          zacc += wt * (float)krem;
        }
      }
    }
    float Z = zacc;
#pragma unroll
    for (int off = 1; off < 64; off <<= 1) Z += __shfl_xor(Z, off, 64);
    __threadfence_block();
    int n = llen[qi];
    if (n > KSEL) n = KSEL;

    // ---- PV gather: lane = output dim ----
    float accv = 0.f;
    int i = 0;
    for (; i + 4 <= n; i += 4) {
      const int ja = lists[qi * KSEL + i + 0];
      const int jb = lists[qi * KSEL + i + 1];
      const int jc = lists[qi * KSEL + i + 2];
      const int jd = lists[qi * KSEL + i + 3];
      const float wa = wlist[qi * KSEL + i + 0];
      const float wb = wlist[qi * KSEL + i + 1];
      const float wc = wlist[qi * KSEL + i + 2];
      const float wd = wlist[qi * KSEL + i + 3];
      const float va = Vg[(size_t)ja * NDIM + lane];
      const float vb = Vg[(size_t)jb * NDIM + lane];
      const float vc = Vg[(size_t)jc * NDIM + lane];
      const float vd = Vg[(size_t)jd * NDIM + lane];
      accv += wa * va + wb * vb + wc * vc + wd * vd;
    }
    for (; i < n; ++i) {
      const int j = lists[qi * KSEL + i];
      accv += wlist[qi * KSEL + i] * Vg[(size_t)j * NDIM + lane];
    }
    Out[((size_t)(bh * LQ + q)) * NDIM + lane] = accv / Z;
  }
}

extern "C" void kernel_launch(void* const* d_in, const int* in_sizes, int n_in,
                              void* d_out, int out_size, void* d_ws, size_t ws_size,
                              hipStream_t stream) {
  (void)in_sizes; (void)n_in; (void)d_ws; (void)ws_size; (void)out_size;
  const float* Q = (const float*)d_in[0];
  const float* K = (const float*)d_in[1];
  const float* V = (const float*)d_in[2];
  float* Out = (float*)d_out;

  (void)hipFuncSetAttribute(reinterpret_cast<const void*>(&topk_attn),
                            hipFuncAttributeMaxDynamicSharedMemorySize, LDS_BYTES);

  topk_attn<<<dim3(8192), NTHREADS, LDS_BYTES, stream>>>(Q, K, V, Out);
}

// Round 3
// 2657.502 us; speedup vs baseline: 3.5000x; 1.2995x over previous
//
#include <hip/hip_runtime.h>
#include <float.h>
#include <stdint.h>

#define QB        16
#define NTHREADS  512
#define LQ        2048
#define NDIM      64
#define KSEL      128
#define LDS_BYTES 147520

// Order-preserving map fp32 -> uint32 (monotone increasing)
__device__ __forceinline__ unsigned ordf(float f) {
  unsigned u = __float_as_uint(f);
  return (u & 0x80000000u) ? ~u : (u | 0x80000000u);
}
__device__ __forceinline__ float unordf(unsigned u) {
  unsigned x = (u & 0x80000000u) ? (u & 0x7FFFFFFFu) : ~u;
  return __uint_as_float(x);
}

extern "C" __global__ void __launch_bounds__(NTHREADS, 2)
topk_attn(const float* __restrict__ Qg_, const float* __restrict__ Kg_,
          const float* __restrict__ Vg_, float* __restrict__ Out) {
  extern __shared__ char lds[];
  float* s_phys = (float*)(lds);            // [QB][LQ] plain layout s[q][j], 131072 B
  int*   lists  = (int*)(lds + 131072);     // [QB][KSEL]  8192 B
  float* wlist  = (float*)(lds + 139264);   // [QB][KSEL]  8192 B
  int*   llen   = (int*)(lds + 147456);     // [QB]          64 B
  float* qs     = (float*)(lds + 131072);   // overlay on lists: QK phase only, 4096 B

  // ---- XCD-aware swizzle: 16 consecutive blocks per XCD share one (b,h) ----
  const int id  = blockIdx.x;
  const int xcd = id & 7;
  const int w   = id >> 3;
  const int bh  = w >> 4;
  const int qb  = ((w & 15) << 3) + xcd;

  const int q0   = qb * QB;
  const int tid  = threadIdx.x;
  const int lane = tid & 63;
  const int wid  = tid >> 6;

  const float* Qg = Qg_ + ((size_t)(bh * LQ + q0)) * NDIM;
  const float* Kg = Kg_ + ((size_t)bh) * LQ * NDIM;
  const float* Vg = Vg_ + ((size_t)bh) * LQ * NDIM;

  // ---- stage Q block into LDS (coalesced float4) ----
  if (tid < QB * NDIM / 4) ((float4*)qs)[tid] = ((const float4*)Qg)[tid];
  __syncthreads();

  // ---- QK^T: 8q x 8k register microtile per thread, spill-free ----
  const int tq   = tid >> 8;      // 0..1  (query group of 8)
  const int tk   = tid & 255;     // 0..255 (key group of 8)
  const int j0   = tk << 3;
  const int qmax = q0 + QB - 1;
  const bool active = (j0 <= qmax);

  float acc[8][8];
#pragma unroll
  for (int i = 0; i < 8; ++i)
#pragma unroll
    for (int j = 0; j < 8; ++j) acc[i][j] = 0.f;

  if (active) {
    const float4* K4  = (const float4*)(Kg + (size_t)j0 * NDIM);
    const float4* qs4 = (const float4*)(qs + tq * 8 * NDIM);
#pragma unroll 1
    for (int d4 = 0; d4 < 16; ++d4) {
      float4 qv[8];
#pragma unroll
      for (int i = 0; i < 8; ++i) qv[i] = qs4[i * 16 + d4];
#pragma unroll
      for (int g = 0; g < 4; ++g) {
        const float4 k0 = K4[(2 * g + 0) * 16 + d4];
        const float4 k1 = K4[(2 * g + 1) * 16 + d4];
#pragma unroll
        for (int i = 0; i < 8; ++i) {
          acc[i][2 * g + 0] += qv[i].x * k0.x + qv[i].y * k0.y +
                               qv[i].z * k0.z + qv[i].w * k0.w;
          acc[i][2 * g + 1] += qv[i].x * k1.x + qv[i].y * k1.y +
                               qv[i].z * k1.z + qv[i].w * k1.w;
        }
      }
    }
  }
  __syncthreads();  // qs reads done before lists overlay gets written later

  // ---- write scores to LDS, plain layout, vectorized b128 writes ----
#pragma unroll
  for (int i = 0; i < 8; ++i) {
    const int q = q0 + tq * 8 + i;
    float4* srow4 = (float4*)(s_phys + (tq * 8 + i) * LQ);
    float4 lo, hi;
    lo.x = (j0 + 0 <= q) ? acc[i][0] : -FLT_MAX;
    lo.y = (j0 + 1 <= q) ? acc[i][1] : -FLT_MAX;
    lo.z = (j0 + 2 <= q) ? acc[i][2] : -FLT_MAX;
    lo.w = (j0 + 3 <= q) ? acc[i][3] : -FLT_MAX;
    hi.x = (j0 + 4 <= q) ? acc[i][4] : -FLT_MAX;
    hi.y = (j0 + 5 <= q) ? acc[i][5] : -FLT_MAX;
    hi.z = (j0 + 6 <= q) ? acc[i][6] : -FLT_MAX;
    hi.w = (j0 + 7 <= q) ? acc[i][7] : -FLT_MAX;
    srow4[tk * 2 + 0] = lo;
    srow4[tk * 2 + 1] = hi;
  }
  __syncthreads();

  // ---- per-wave: register-resident exact top-128 + softmax + PV gather ----
  const float C = 0.18033688011112042f; // 0.125 * log2(e)

  for (int qi = wid; qi < QB; qi += 8) {
    const int q = q0 + qi;
    const float* srow = s_phys + qi * LQ;
    const float4* srow4 = (const float4*)srow;

    // load 32 scores into registers (conflict-free b128), as ordered uints
    unsigned u[32];
#pragma unroll
    for (int i = 0; i < 8; ++i) {
      const float4 v = srow4[lane + (i << 6)];
      u[4 * i + 0] = ordf(v.x);
      u[4 * i + 1] = ordf(v.y);
      u[4 * i + 2] = ordf(v.z);
      u[4 * i + 3] = ordf(v.w);
    }

    // exact 128th-largest: 32-round bitwise radix descent, ballot counting.
    // invariant: count(u >= p|bit) = cnt1 + (KSEL - k)  => descend-1 iff cnt >= KSEL
    unsigned p = 0;
    int k = KSEL;
#pragma unroll 1
    for (int b = 31; b >= 0; --b) {
      const unsigned T = p | (1u << b);
      int cnt = 0;
#pragma unroll
      for (int i = 0; i < 32; ++i)
        cnt += (int)__popcll(__ballot(u[i] >= T));
      if (cnt >= KSEL) p = T;
      else             k = KSEL - cnt;
    }
    const unsigned tu = p;           // exact 128th-largest value (ordered space)
    const int krem = k;              // how many ==tu belong in the top-128
    const float tf = unordf(tu);
    const float wt = exp2f(tf * C);  // exactly 0 for -FLT_MAX threshold (q<127 rows)

    if (lane == 0) llen[qi] = 0;
    __threadfence_block();

    // collect strict-greater (count = KSEL - krem <= 127, no bound check needed)
    float zacc = 0.f;
    int myeq = 0;
#pragma unroll
    for (int i = 0; i < 32; ++i) {
      const unsigned ui = u[i];
      if (ui > tu) {
        const int pos = atomicAdd(&llen[qi], 1);
        const int j = ((i >> 2) << 8) + (lane << 2) + (i & 3);
        const float wv = exp2f(unordf(ui) * C);
        lists[qi * KSEL + pos] = j;
        wlist[qi * KSEL + pos] = wv;
        zacc += wv;
      } else if (ui == tu) {
        myeq++;
      }
    }
    if (wt > 0.f) {
      int te = myeq;
#pragma unroll
      for (int off = 1; off < 64; off <<= 1) te += __shfl_xor(te, off, 64);
      if (te == krem) {
        // common case: include every tied element (total lands exactly at KSEL)
#pragma unroll
        for (int i = 0; i < 32; ++i) {
          if (u[i] == tu) {
            const int pos = atomicAdd(&llen[qi], 1);
            const int j = ((i >> 2) << 8) + (lane << 2) + (i & 3);
            lists[qi * KSEL + pos] = j;
            wlist[qi * KSEL + pos] = wt;
            zacc += wt;
          }
        }
      } else {
        // rare: more ties than slots -> take smallest indices (reference tie order)
        if (lane == 0) {
          int taken = 0;
          for (int j = 0; j < LQ && taken < krem; ++j) {
            if (ordf(srow[j]) == tu) {
              const int pos = llen[qi];
              llen[qi] = pos + 1;
              lists[qi * KSEL + pos] = j;
              wlist[qi * KSEL + pos] = wt;
              taken++;
            }
          }
          zacc += wt * (float)krem;
        }
      }
    }
    float Z = zacc;
#pragma unroll
    for (int off = 1; off < 64; off <<= 1) Z += __shfl_xor(Z, off, 64);
    __threadfence_block();
    int n = llen[qi];
    if (n > KSEL) n = KSEL;

    // ---- PV gather: lane = output dim; list/weight reads are LDS broadcasts ----
    float accv = 0.f;
    int i = 0;
    for (; i + 4 <= n; i += 4) {
      const int ja = lists[qi * KSEL + i + 0];
      const int jb = lists[qi * KSEL + i + 1];
      const int jc = lists[qi * KSEL + i + 2];
      const int jd = lists[qi * KSEL + i + 3];
      const float wa = wlist[qi * KSEL + i + 0];
      const float wb = wlist[qi * KSEL + i + 1];
      const float wc = wlist[qi * KSEL + i + 2];
      const float wd = wlist[qi * KSEL + i + 3];
      const float va = Vg[(size_t)ja * NDIM + lane];
      const float vb = Vg[(size_t)jb * NDIM + lane];
      const float vc = Vg[(size_t)jc * NDIM + lane];
      const float vd = Vg[(size_t)jd * NDIM + lane];
      accv += wa * va + wb * vb + wc * vc + wd * vd;
    }
    for (; i < n; ++i) {
      const int j = lists[qi * KSEL + i];
      accv += wlist[qi * KSEL + i] * Vg[(size_t)j * NDIM + lane];
    }
    Out[((size_t)(bh * LQ + q)) * NDIM + lane] = accv / Z;
  }
}

extern "C" void kernel_launch(void* const* d_in, const int* in_sizes, int n_in,
                              void* d_out, int out_size, void* d_ws, size_t ws_size,
                              hipStream_t stream) {
  (void)in_sizes; (void)n_in; (void)d_ws; (void)ws_size; (void)out_size;
  const float* Q = (const float*)d_in[0];
  const float* K = (const float*)d_in[1];
  const float* V = (const float*)d_in[2];
  float* Out = (float*)d_out;

  (void)hipFuncSetAttribute(reinterpret_cast<const void*>(&topk_attn),
                            hipFuncAttributeMaxDynamicSharedMemorySize, LDS_BYTES);

  topk_attn<<<dim3(8192), NTHREADS, LDS_BYTES, stream>>>(Q, K, V, Out);
}

// Round 4
// 2457.507 us; speedup vs baseline: 3.7849x; 1.0814x over previous
//
#include <hip/hip_runtime.h>
#include <float.h>
#include <stdint.h>

#define QB        8
#define NTHREADS  512
#define LQ        2048
#define NDIM      64
#define KSEL      128
#define LDS_BYTES 73760

// Order-preserving map fp32 -> uint32 (monotone increasing)
__device__ __forceinline__ unsigned ordf(float f) {
  unsigned u = __float_as_uint(f);
  return (u & 0x80000000u) ? ~u : (u | 0x80000000u);
}
__device__ __forceinline__ float unordf(unsigned u) {
  unsigned x = (u & 0x80000000u) ? (u & 0x7FFFFFFFu) : ~u;
  return __uint_as_float(x);
}

extern "C" __global__ void __launch_bounds__(NTHREADS, 4)
topk_attn(const float* __restrict__ Qg_, const float* __restrict__ Kg_,
          const float* __restrict__ Vg_, float* __restrict__ Out) {
  extern __shared__ char lds[];
  float* s_phys = (float*)(lds);            // [QB][LQ] plain layout, 65536 B
  int*   lists  = (int*)(lds + 65536);      // [QB][KSEL]  4096 B
  float* wlist  = (float*)(lds + 69632);    // [QB][KSEL]  4096 B
  float* qs     = (float*)(lds + 65536);    // overlay on lists (QK phase only), 2048 B

  // ---- XCD-aware swizzle: 32 consecutive blocks per XCD share one (b,h) ----
  const int id  = blockIdx.x;
  const int xcd = id & 7;
  const int w   = id >> 3;
  const int bh  = w >> 5;                  // 0..63
  const int qb  = ((w & 31) << 3) + xcd;   // 0..255, bijective

  const int q0   = qb * QB;
  const int tid  = threadIdx.x;
  const int lane = tid & 63;
  const int wid  = tid >> 6;

  const float* Qg = Qg_ + ((size_t)(bh * LQ + q0)) * NDIM;
  const float* Kg = Kg_ + ((size_t)bh) * LQ * NDIM;
  const float* Vg = Vg_ + ((size_t)bh) * LQ * NDIM;

  // ---- stage Q block into LDS (coalesced float4) ----
  if (tid < QB * NDIM / 4) ((float4*)qs)[tid] = ((const float4*)Qg)[tid];
  __syncthreads();

  // ---- QK^T: 4q x 8k register microtile per thread, spill-free ----
  const int tq   = tid >> 8;      // 0..1  (query group of 4)
  const int tk   = tid & 255;     // 0..255 (key group of 8)
  const int j0   = tk << 3;
  const int qmax = q0 + QB - 1;
  const bool active = (j0 <= qmax);

  float acc[4][8];
#pragma unroll
  for (int i = 0; i < 4; ++i)
#pragma unroll
    for (int j = 0; j < 8; ++j) acc[i][j] = 0.f;

  if (active) {
    const float4* K4  = (const float4*)(Kg + (size_t)j0 * NDIM);
    const float4* qs4 = (const float4*)(qs + tq * 4 * NDIM);
#pragma unroll 1
    for (int d4 = 0; d4 < 16; ++d4) {
      float4 qv[4];
#pragma unroll
      for (int i = 0; i < 4; ++i) qv[i] = qs4[i * 16 + d4];
#pragma unroll
      for (int g = 0; g < 4; ++g) {
        const float4 k0 = K4[(2 * g + 0) * 16 + d4];
        const float4 k1 = K4[(2 * g + 1) * 16 + d4];
#pragma unroll
        for (int i = 0; i < 4; ++i) {
          acc[i][2 * g + 0] += qv[i].x * k0.x + qv[i].y * k0.y +
                               qv[i].z * k0.z + qv[i].w * k0.w;
          acc[i][2 * g + 1] += qv[i].x * k1.x + qv[i].y * k1.y +
                               qv[i].z * k1.z + qv[i].w * k1.w;
        }
      }
    }
  }
  __syncthreads();  // qs reads done before lists overlay is written

  // ---- write scores to LDS, plain layout, vectorized b128 writes ----
#pragma unroll
  for (int i = 0; i < 4; ++i) {
    const int q = q0 + tq * 4 + i;
    float4* srow4 = (float4*)(s_phys + (tq * 4 + i) * LQ);
    float4 lo, hi;
    lo.x = (j0 + 0 <= q) ? acc[i][0] : -FLT_MAX;
    lo.y = (j0 + 1 <= q) ? acc[i][1] : -FLT_MAX;
    lo.z = (j0 + 2 <= q) ? acc[i][2] : -FLT_MAX;
    lo.w = (j0 + 3 <= q) ? acc[i][3] : -FLT_MAX;
    hi.x = (j0 + 4 <= q) ? acc[i][4] : -FLT_MAX;
    hi.y = (j0 + 5 <= q) ? acc[i][5] : -FLT_MAX;
    hi.z = (j0 + 6 <= q) ? acc[i][6] : -FLT_MAX;
    hi.w = (j0 + 7 <= q) ? acc[i][7] : -FLT_MAX;
    srow4[tk * 2 + 0] = lo;
    srow4[tk * 2 + 1] = hi;
  }
  __syncthreads();

  // ---- per-wave: one query each; register top-128 + softmax + PV gather ----
  const float C = 0.18033688011112042f; // 0.125 * log2(e)
  const int qi = wid;                   // 8 waves <-> 8 queries
  const int q = q0 + qi;
  const float* srow = s_phys + qi * LQ;
  const float4* srow4 = (const float4*)srow;

  // load 32 scores into registers (conflict-free b128), as ordered uints
  unsigned u[32];
#pragma unroll
  for (int i = 0; i < 8; ++i) {
    const float4 v = srow4[lane + (i << 6)];
    u[4 * i + 0] = ordf(v.x);
    u[4 * i + 1] = ordf(v.y);
    u[4 * i + 2] = ordf(v.z);
    u[4 * i + 3] = ordf(v.w);
  }

  // exact 128th-largest: 32-round bitwise radix descent, ballot counting
  unsigned p = 0;
  int k = KSEL;
#pragma unroll 1
  for (int b = 31; b >= 0; --b) {
    const unsigned T = p | (1u << b);
    int cnt = 0;
#pragma unroll
    for (int i = 0; i < 32; ++i)
      cnt += (int)__popcll(__ballot(u[i] >= T));
    if (cnt >= KSEL) p = T;
    else             k = KSEL - cnt;
  }
  const unsigned tu = p;           // exact 128th-largest value (ordered space)
  const int krem = k;              // how many ==tu belong in the top-128
  const float tf = unordf(tu);
  const float wt = exp2f(tf * C);  // exactly 0 for -FLT_MAX threshold (q<127)

  // ---- collect via ballot-prefix positions (no atomics) ----
  const unsigned long long ltmask = (1ull << lane) - 1ull;
  float zacc = 0.f;
  int myeq = 0;
  int base = 0;
#pragma unroll
  for (int i = 0; i < 32; ++i) {
    const unsigned ui = u[i];
    const unsigned long long b = __ballot(ui > tu);
    if (ui > tu) {
      const int pos = base + (int)__popcll(b & ltmask);
      const int j = ((i >> 2) << 8) + (lane << 2) + (i & 3);
      const float wv = exp2f(unordf(ui) * C);
      lists[qi * KSEL + pos] = j;
      wlist[qi * KSEL + pos] = wv;
      zacc += wv;
    }
    base += (int)__popcll(b);
    myeq += (ui == tu) ? 1 : 0;
  }
  int n = base;                    // = KSEL - krem
  if (wt > 0.f) {
    int te = myeq;
#pragma unroll
    for (int off = 1; off < 64; off <<= 1) te += __shfl_xor(te, off, 64);
    if (te == krem) {
      // common case: include every tied element (lands exactly at KSEL)
#pragma unroll
      for (int i = 0; i < 32; ++i) {
        const unsigned long long b = __ballot(u[i] == tu);
        if (u[i] == tu) {
          const int pos = base + (int)__popcll(b & ltmask);
          const int j = ((i >> 2) << 8) + (lane << 2) + (i & 3);
          lists[qi * KSEL + pos] = j;
          wlist[qi * KSEL + pos] = wt;
          zacc += wt;
        }
        base += (int)__popcll(b);
      }
      n = base;                    // == KSEL
    } else {
      // rare: more ties than slots -> take smallest indices (reference order)
      if (lane == 0) {
        int taken = 0, pos = base;
        for (int j = 0; j < LQ && taken < krem; ++j) {
          if (ordf(srow[j]) == tu) {
            lists[qi * KSEL + pos] = j;
            wlist[qi * KSEL + pos] = wt;
            pos++; taken++;
          }
        }
        zacc += wt * (float)krem;
      }
      n = KSEL;
    }
  }
  float Z = zacc;
#pragma unroll
  for (int off = 1; off < 64; off <<= 1) Z += __shfl_xor(Z, off, 64);
  __threadfence_block();  // make cross-lane LDS writes visible before gather

  // ---- PV gather: lane = output dim; prefetch 8 (idx,w) pairs per iter ----
  float accv = 0.f;
  int i = 0;
  for (; i + 8 <= n; i += 8) {
    const int4   ja = *(const int4*)  &lists[qi * KSEL + i];
    const int4   jb = *(const int4*)  &lists[qi * KSEL + i + 4];
    const float4 wa = *(const float4*)&wlist[qi * KSEL + i];
    const float4 wb = *(const float4*)&wlist[qi * KSEL + i + 4];
    const float v0 = Vg[(size_t)ja.x * NDIM + lane];
    const float v1 = Vg[(size_t)ja.y * NDIM + lane];
    const float v2 = Vg[(size_t)ja.z * NDIM + lane];
    const float v3 = Vg[(size_t)ja.w * NDIM + lane];
    const float v4 = Vg[(size_t)jb.x * NDIM + lane];
    const float v5 = Vg[(size_t)jb.y * NDIM + lane];
    const float v6 = Vg[(size_t)jb.z * NDIM + lane];
    const float v7 = Vg[(size_t)jb.w * NDIM + lane];
    accv += wa.x * v0 + wa.y * v1 + wa.z * v2 + wa.w * v3 +
            wb.x * v4 + wb.y * v5 + wb.z * v6 + wb.w * v7;
  }
  for (; i < n; ++i) {
    const int j = lists[qi * KSEL + i];
    accv += wlist[qi * KSEL + i] * Vg[(size_t)j * NDIM + lane];
  }
  Out[((size_t)(bh * LQ + q)) * NDIM + lane] = accv / Z;
}

extern "C" void kernel_launch(void* const* d_in, const int* in_sizes, int n_in,
                              void* d_out, int out_size, void* d_ws, size_t ws_size,
                              hipStream_t stream) {
  (void)in_sizes; (void)n_in; (void)d_ws; (void)ws_size; (void)out_size;
  const float* Q = (const float*)d_in[0];
  const float* K = (const float*)d_in[1];
  const float* V = (const float*)d_in[2];
  float* Out = (float*)d_out;

  (void)hipFuncSetAttribute(reinterpret_cast<const void*>(&topk_attn),
                            hipFuncAttributeMaxDynamicSharedMemorySize, LDS_BYTES);

  topk_attn<<<dim3(16384), NTHREADS, LDS_BYTES, stream>>>(Q, K, V, Out);
}

// Round 5
// 1624.146 us; speedup vs baseline: 5.7269x; 1.5131x over previous
//
#include <hip/hip_runtime.h>
#include <float.h>
#include <stdint.h>

#define QB        16
#define NTHREADS  512
#define LQ        2048
#define NDIM      64
#define KSEL      128
#define LDS_BYTES 151552
#define WS_NEEDED (2u * 8388608u * 2u)   // Khi + Klo, bf16 each: 33.6 MB

typedef __attribute__((ext_vector_type(8))) short  s8v;   // 8 bf16 (4 VGPRs)
typedef __attribute__((ext_vector_type(4))) float  f32x4; // MFMA C/D

// Order-preserving map fp32 -> uint32 (monotone increasing)
__device__ __forceinline__ unsigned ordf(float f) {
  unsigned u = __float_as_uint(f);
  return (u & 0x80000000u) ? ~u : (u | 0x80000000u);
}
__device__ __forceinline__ float unordf(unsigned u) {
  unsigned x = (u & 0x80000000u) ? (u & 0x7FFFFFFFu) : ~u;
  return __uint_as_float(x);
}
__device__ __forceinline__ unsigned short f2bf(float f) {  // RNE, no NaN in data
  unsigned u = __float_as_uint(f);
  return (unsigned short)((u + 0x7FFFu + ((u >> 16) & 1u)) >> 16);
}
__device__ __forceinline__ float bf2f(unsigned short h) {
  return __uint_as_float(((unsigned)h) << 16);
}

// ---- prepass: K fp32 -> (Khi, Klo) bf16 split, one-time ----
extern "C" __global__ void __launch_bounds__(256)
convert_k(const float4* __restrict__ K4, ushort4* __restrict__ Khi,
          ushort4* __restrict__ Klo) {
  const int idx = blockIdx.x * 256 + threadIdx.x;   // 0 .. 2097151
  const float4 f = K4[idx];
  ushort4 h, l;
  h.x = f2bf(f.x); l.x = f2bf(f.x - bf2f(h.x));
  h.y = f2bf(f.y); l.y = f2bf(f.y - bf2f(h.y));
  h.z = f2bf(f.z); l.z = f2bf(f.z - bf2f(h.z));
  h.w = f2bf(f.w); l.w = f2bf(f.w - bf2f(h.w));
  Khi[idx] = h;
  Klo[idx] = l;
}

extern "C" __global__ void __launch_bounds__(NTHREADS, 2)
topk_attn_mfma(const float* __restrict__ Qg_, const float* __restrict__ Vg_,
               const unsigned short* __restrict__ Khi_,
               const unsigned short* __restrict__ Klo_,
               float* __restrict__ Out) {
  extern __shared__ char lds[];
  float*          s_phys = (float*)(lds);            // [QB][LQ] 131072 B
  unsigned short* qs_hi  = (unsigned short*)(lds + 131072);  // [QB][NDIM] 2048 B
  unsigned short* qs_lo  = (unsigned short*)(lds + 133120);  // 2048 B
  int*            lists  = (int*)(lds + 135168);     // [QB][KSEL] 8192 B
  float*          wlist  = (float*)(lds + 143360);   // 8192 B

  // ---- XCD-aware swizzle: 16 consecutive blocks per XCD share one (b,h) ----
  const int id  = blockIdx.x;
  const int xcd = id & 7;
  const int w   = id >> 3;
  const int bh  = w >> 4;                  // 0..63
  const int qb  = ((w & 15) << 3) + xcd;   // 0..127, bijective

  const int q0   = qb * QB;
  const int tid  = threadIdx.x;
  const int lane = tid & 63;
  const int wid  = tid >> 6;
  const int m16  = lane & 15;
  const int quad = lane >> 4;

  const float* Qg  = Qg_ + ((size_t)(bh * LQ + q0)) * NDIM;
  const float* Vg  = Vg_ + ((size_t)bh) * LQ * NDIM;
  const unsigned short* Khi = Khi_ + ((size_t)bh) * LQ * NDIM;
  const unsigned short* Klo = Klo_ + ((size_t)bh) * LQ * NDIM;

  // ---- stage Q block, bf16-split, into LDS ----
#pragma unroll
  for (int e = tid; e < QB * NDIM; e += NTHREADS) {
    const float f = Qg[e];
    const unsigned short h = f2bf(f);
    qs_hi[e] = h;
    qs_lo[e] = f2bf(f - bf2f(h));
  }
  __syncthreads();

  // ---- A fragments (Q), held in registers for all tiles ----
  // A[m=lane&15][k=quad*8+j], k-halves at d=0 and d=32
  const unsigned short* qh = qs_hi + m16 * NDIM + quad * 8;
  const unsigned short* ql = qs_lo + m16 * NDIM + quad * 8;
  const s8v Ah0 = *(const s8v*)qh;
  const s8v Ah1 = *(const s8v*)(qh + 32);
  const s8v Al0 = *(const s8v*)ql;
  const s8v Al1 = *(const s8v*)(ql + 32);

  // ---- QK^T via MFMA: wave handles key tiles jt = wid + 8*t ----
#pragma unroll 2
  for (int t = 0; t < 16; ++t) {
    const int jt = wid + 8 * t;            // 0..127
    const int jc = jt * 16 + m16;          // this lane's key column
    if (jt > qb) {
      // fully masked tile: write -FLT_MAX
#pragma unroll
      for (int reg = 0; reg < 4; ++reg)
        s_phys[(quad * 4 + reg) * LQ + jc] = -FLT_MAX;
      continue;
    }
    // B[k=quad*8+j][n=lane&15] = K[jt*16+n][half*32 + quad*8 + j] (contiguous)
    const unsigned short* kh = Khi + (size_t)(jt * 16 + m16) * NDIM + quad * 8;
    const unsigned short* kl = Klo + (size_t)(jt * 16 + m16) * NDIM + quad * 8;
    const s8v Bh0 = *(const s8v*)kh;
    const s8v Bh1 = *(const s8v*)(kh + 32);
    const s8v Bl0 = *(const s8v*)kl;
    const s8v Bl1 = *(const s8v*)(kl + 32);
    f32x4 c = {0.f, 0.f, 0.f, 0.f};
    c = __builtin_amdgcn_mfma_f32_16x16x32_bf16(Ah0, Bh0, c, 0, 0, 0);
    c = __builtin_amdgcn_mfma_f32_16x16x32_bf16(Ah1, Bh1, c, 0, 0, 0);
    c = __builtin_amdgcn_mfma_f32_16x16x32_bf16(Ah0, Bl0, c, 0, 0, 0);
    c = __builtin_amdgcn_mfma_f32_16x16x32_bf16(Ah1, Bl1, c, 0, 0, 0);
    c = __builtin_amdgcn_mfma_f32_16x16x32_bf16(Al0, Bh0, c, 0, 0, 0);
    c = __builtin_amdgcn_mfma_f32_16x16x32_bf16(Al1, Bh1, c, 0, 0, 0);
    // C/D: col=lane&15 (key), row=quad*4+reg (query); causal mask at write
#pragma unroll
    for (int reg = 0; reg < 4; ++reg) {
      const int r = quad * 4 + reg;
      s_phys[r * LQ + jc] = (jc <= q0 + r) ? c[reg] : -FLT_MAX;
    }
  }
  __syncthreads();

  // ---- per-wave: two queries (wid, wid+8); register top-128 + softmax + PV ----
  const float C = 0.18033688011112042f; // 0.125 * log2(e)
  const unsigned long long ltmask = (1ull << lane) - 1ull;

  for (int qi = wid; qi < QB; qi += 8) {
    const int q = q0 + qi;
    const float* srow = s_phys + qi * LQ;
    const float4* srow4 = (const float4*)srow;
    const int g8 = q >> 8;   // causal bound: groups i8 <= g8 contain valid keys

    // load scores (conflict-free b128) as ordered uints; u[4*i8+c] <-> j = i8*256+lane*4+c
    unsigned u[32];
#pragma unroll
    for (int i8 = 0; i8 < 8; ++i8) {
      if (i8 <= g8) {
        const float4 v = srow4[lane + (i8 << 6)];
        u[4 * i8 + 0] = ordf(v.x);
        u[4 * i8 + 1] = ordf(v.y);
        u[4 * i8 + 2] = ordf(v.z);
        u[4 * i8 + 3] = ordf(v.w);
      } else {
        u[4 * i8 + 0] = u[4 * i8 + 1] = u[4 * i8 + 2] = u[4 * i8 + 3] = 0u;
      }
    }

    // exact 128th-largest: bitwise radix descent, ballot counting, causal-bounded
    unsigned p = 0;
    int k = KSEL;
#pragma unroll 1
    for (int b = 31; b >= 0; --b) {
      const unsigned T = p | (1u << b);
      int cnt = 0;
#pragma unroll
      for (int i8 = 0; i8 < 8; ++i8) {
        if (i8 <= g8) {
          cnt += (int)__popcll(__ballot(u[4 * i8 + 0] >= T));
          cnt += (int)__popcll(__ballot(u[4 * i8 + 1] >= T));
          cnt += (int)__popcll(__ballot(u[4 * i8 + 2] >= T));
          cnt += (int)__popcll(__ballot(u[4 * i8 + 3] >= T));
        }
      }
      if (cnt >= KSEL) p = T;
      else             k = KSEL - cnt;
    }
    const unsigned tu = p;
    const int krem = k;
    const float wt = exp2f(unordf(tu) * C);  // exactly 0 for masked threshold

    // ---- collect via ballot-prefix positions (no atomics) ----
    float zacc = 0.f;
    int myeq = 0;
    int base = 0;
#pragma unroll
    for (int i8 = 0; i8 < 8; ++i8) {
      if (i8 > g8) break;
#pragma unroll
      for (int c4 = 0; c4 < 4; ++c4) {
        const unsigned ui = u[4 * i8 + c4];
        const unsigned long long b = __ballot(ui > tu);
        if (ui > tu) {
          const int pos = base + (int)__popcll(b & ltmask);
          const int j = i8 * 256 + (lane << 2) + c4;
          const float wv = exp2f(unordf(ui) * C);
          lists[qi * KSEL + pos] = j;
          wlist[qi * KSEL + pos] = wv;
          zacc += wv;
        }
        base += (int)__popcll(b);
        myeq += (ui == tu) ? 1 : 0;
      }
    }
    int n = base;                    // = KSEL - krem (or q+1 when q < KSEL-1)
    if (wt > 0.f) {
      int te = myeq;
#pragma unroll
      for (int off = 1; off < 64; off <<= 1) te += __shfl_xor(te, off, 64);
      if (te == krem) {
#pragma unroll
        for (int i8 = 0; i8 < 8; ++i8) {
          if (i8 > g8) break;
#pragma unroll
          for (int c4 = 0; c4 < 4; ++c4) {
            const unsigned ui = u[4 * i8 + c4];
            const unsigned long long b = __ballot(ui == tu);
            if (ui == tu) {
              const int pos = base + (int)__popcll(b & ltmask);
              const int j = i8 * 256 + (lane << 2) + c4;
              lists[qi * KSEL + pos] = j;
              wlist[qi * KSEL + pos] = wt;
              zacc += wt;
            }
            base += (int)__popcll(b);
          }
        }
        n = base;
      } else {
        // rare: more ties than slots -> take smallest indices (reference order)
        if (lane == 0) {
          int taken = 0, pos = base;
          for (int j = 0; j < LQ && taken < krem; ++j) {
            if (ordf(srow[j]) == tu) {
              lists[qi * KSEL + pos] = j;
              wlist[qi * KSEL + pos] = wt;
              pos++; taken++;
            }
          }
          zacc += wt * (float)krem;
        }
        n = KSEL;
      }
    }
    float Z = zacc;
#pragma unroll
    for (int off = 1; off < 64; off <<= 1) Z += __shfl_xor(Z, off, 64);
    __threadfence_block();

    // ---- PV gather: lane = output dim; 16 loads in flight per iter ----
    float accv = 0.f;
    int i = 0;
    for (; i + 16 <= n; i += 16) {
      int4   jv[4];
      float4 wv[4];
#pragma unroll
      for (int g = 0; g < 4; ++g) {
        jv[g] = *(const int4*)  &lists[qi * KSEL + i + 4 * g];
        wv[g] = *(const float4*)&wlist[qi * KSEL + i + 4 * g];
      }
      float v[16];
#pragma unroll
      for (int g = 0; g < 4; ++g) {
        v[4 * g + 0] = Vg[(size_t)jv[g].x * NDIM + lane];
        v[4 * g + 1] = Vg[(size_t)jv[g].y * NDIM + lane];
        v[4 * g + 2] = Vg[(size_t)jv[g].z * NDIM + lane];
        v[4 * g + 3] = Vg[(size_t)jv[g].w * NDIM + lane];
      }
#pragma unroll
      for (int g = 0; g < 4; ++g)
        accv += wv[g].x * v[4 * g + 0] + wv[g].y * v[4 * g + 1] +
                wv[g].z * v[4 * g + 2] + wv[g].w * v[4 * g + 3];
    }
    for (; i < n; ++i) {
      const int j = lists[qi * KSEL + i];
      accv += wlist[qi * KSEL + i] * Vg[(size_t)j * NDIM + lane];
    }
    Out[((size_t)(bh * LQ + q)) * NDIM + lane] = accv / Z;
  }
}

// ================= fallback (round-4 kernel, used if ws too small) =========
#define FB_QB        8
#define FB_LDS_BYTES 73760

extern "C" __global__ void __launch_bounds__(NTHREADS, 4)
topk_attn_fb(const float* __restrict__ Qg_, const float* __restrict__ Kg_,
             const float* __restrict__ Vg_, float* __restrict__ Out) {
  extern __shared__ char lds[];
  float* s_phys = (float*)(lds);
  int*   lists  = (int*)(lds + 65536);
  float* wlist  = (float*)(lds + 69632);
  float* qs     = (float*)(lds + 65536);

  const int id  = blockIdx.x;
  const int xcd = id & 7;
  const int w   = id >> 3;
  const int bh  = w >> 5;
  const int qb  = ((w & 31) << 3) + xcd;

  const int q0   = qb * FB_QB;
  const int tid  = threadIdx.x;
  const int lane = tid & 63;
  const int wid  = tid >> 6;

  const float* Qg = Qg_ + ((size_t)(bh * LQ + q0)) * NDIM;
  const float* Kg = Kg_ + ((size_t)bh) * LQ * NDIM;
  const float* Vg = Vg_ + ((size_t)bh) * LQ * NDIM;

  if (tid < FB_QB * NDIM / 4) ((float4*)qs)[tid] = ((const float4*)Qg)[tid];
  __syncthreads();

  const int tq   = tid >> 8;
  const int tk   = tid & 255;
  const int j0   = tk << 3;
  const int qmax = q0 + FB_QB - 1;
  const bool active = (j0 <= qmax);

  float acc[4][8];
#pragma unroll
  for (int i = 0; i < 4; ++i)
#pragma unroll
    for (int j = 0; j < 8; ++j) acc[i][j] = 0.f;

  if (active) {
    const float4* K4  = (const float4*)(Kg + (size_t)j0 * NDIM);
    const float4* qs4 = (const float4*)(qs + tq * 4 * NDIM);
#pragma unroll 1
    for (int d4 = 0; d4 < 16; ++d4) {
      float4 qv[4];
#pragma unroll
      for (int i = 0; i < 4; ++i) qv[i] = qs4[i * 16 + d4];
#pragma unroll
      for (int g = 0; g < 4; ++g) {
        const float4 k0 = K4[(2 * g + 0) * 16 + d4];
        const float4 k1 = K4[(2 * g + 1) * 16 + d4];
#pragma unroll
        for (int i = 0; i < 4; ++i) {
          acc[i][2 * g + 0] += qv[i].x * k0.x + qv[i].y * k0.y +
                               qv[i].z * k0.z + qv[i].w * k0.w;
          acc[i][2 * g + 1] += qv[i].x * k1.x + qv[i].y * k1.y +
                               qv[i].z * k1.z + qv[i].w * k1.w;
        }
      }
    }
  }
  __syncthreads();

#pragma unroll
  for (int i = 0; i < 4; ++i) {
    const int q = q0 + tq * 4 + i;
    float4* srow4 = (float4*)(s_phys + (tq * 4 + i) * LQ);
    float4 lo, hi;
    lo.x = (j0 + 0 <= q) ? acc[i][0] : -FLT_MAX;
    lo.y = (j0 + 1 <= q) ? acc[i][1] : -FLT_MAX;
    lo.z = (j0 + 2 <= q) ? acc[i][2] : -FLT_MAX;
    lo.w = (j0 + 3 <= q) ? acc[i][3] : -FLT_MAX;
    hi.x = (j0 + 4 <= q) ? acc[i][4] : -FLT_MAX;
    hi.y = (j0 + 5 <= q) ? acc[i][5] : -FLT_MAX;
    hi.z = (j0 + 6 <= q) ? acc[i][6] : -FLT_MAX;
    hi.w = (j0 + 7 <= q) ? acc[i][7] : -FLT_MAX;
    srow4[tk * 2 + 0] = lo;
    srow4[tk * 2 + 1] = hi;
  }
  __syncthreads();

  const float C = 0.18033688011112042f;
  const int qi = wid;
  const int q = q0 + qi;
  const float* srow = s_phys + qi * LQ;
  const float4* srow4 = (const float4*)srow;

  unsigned u[32];
#pragma unroll
  for (int i = 0; i < 8; ++i) {
    const float4 v = srow4[lane + (i << 6)];
    u[4 * i + 0] = ordf(v.x);
    u[4 * i + 1] = ordf(v.y);
    u[4 * i + 2] = ordf(v.z);
    u[4 * i + 3] = ordf(v.w);
  }

  unsigned p = 0;
  int k = KSEL;
#pragma unroll 1
  for (int b = 31; b >= 0; --b) {
    const unsigned T = p | (1u << b);
    int cnt = 0;
#pragma unroll
    for (int i = 0; i < 32; ++i)
      cnt += (int)__popcll(__ballot(u[i] >= T));
    if (cnt >= KSEL) p = T;
    else             k = KSEL - cnt;
  }
  const unsigned tu = p;
  const int krem = k;
  const float wt = exp2f(unordf(tu) * C);

  const unsigned long long ltmask = (1ull << lane) - 1ull;
  float zacc = 0.f;
  int myeq = 0;
  int base = 0;
#pragma unroll
  for (int i = 0; i < 32; ++i) {
    const unsigned ui = u[i];
    const unsigned long long b = __ballot(ui > tu);
    if (ui > tu) {
      const int pos = base + (int)__popcll(b & ltmask);
      const int j = ((i >> 2) << 8) + (lane << 2) + (i & 3);
      const float wv = exp2f(unordf(ui) * C);
      lists[qi * KSEL + pos] = j;
      wlist[qi * KSEL + pos] = wv;
      zacc += wv;
    }
    base += (int)__popcll(b);
    myeq += (ui == tu) ? 1 : 0;
  }
  int n = base;
  if (wt > 0.f) {
    int te = myeq;
#pragma unroll
    for (int off = 1; off < 64; off <<= 1) te += __shfl_xor(te, off, 64);
    if (te == krem) {
#pragma unroll
      for (int i = 0; i < 32; ++i) {
        const unsigned long long b = __ballot(u[i] == tu);
        if (u[i] == tu) {
          const int pos = base + (int)__popcll(b & ltmask);
          const int j = ((i >> 2) << 8) + (lane << 2) + (i & 3);
          lists[qi * KSEL + pos] = j;
          wlist[qi * KSEL + pos] = wt;
          zacc += wt;
        }
        base += (int)__popcll(b);
      }
      n = base;
    } else {
      if (lane == 0) {
        int taken = 0, pos = base;
        for (int j = 0; j < LQ && taken < krem; ++j) {
          if (ordf(srow[j]) == tu) {
            lists[qi * KSEL + pos] = j;
            wlist[qi * KSEL + pos] = wt;
            pos++; taken++;
          }
        }
        zacc += wt * (float)krem;
      }
      n = KSEL;
    }
  }
  float Z = zacc;
#pragma unroll
  for (int off = 1; off < 64; off <<= 1) Z += __shfl_xor(Z, off, 64);
  __threadfence_block();

  float accv = 0.f;
  int i = 0;
  for (; i + 8 <= n; i += 8) {
    const int4   ja = *(const int4*)  &lists[qi * KSEL + i];
    const int4   jb = *(const int4*)  &lists[qi * KSEL + i + 4];
    const float4 wa = *(const float4*)&wlist[qi * KSEL + i];
    const float4 wb = *(const float4*)&wlist[qi * KSEL + i + 4];
    const float v0 = Vg[(size_t)ja.x * NDIM + lane];
    const float v1 = Vg[(size_t)ja.y * NDIM + lane];
    const float v2 = Vg[(size_t)ja.z * NDIM + lane];
    const float v3 = Vg[(size_t)ja.w * NDIM + lane];
    const float v4 = Vg[(size_t)jb.x * NDIM + lane];
    const float v5 = Vg[(size_t)jb.y * NDIM + lane];
    const float v6 = Vg[(size_t)jb.z * NDIM + lane];
    const float v7 = Vg[(size_t)jb.w * NDIM + lane];
    accv += wa.x * v0 + wa.y * v1 + wa.z * v2 + wa.w * v3 +
            wb.x * v4 + wb.y * v5 + wb.z * v6 + wb.w * v7;
  }
  for (; i < n; ++i) {
    const int j = lists[qi * KSEL + i];
    accv += wlist[qi * KSEL + i] * Vg[(size_t)j * NDIM + lane];
  }
  Out[((size_t)(bh * LQ + q)) * NDIM + lane] = accv / Z;
}

extern "C" void kernel_launch(void* const* d_in, const int* in_sizes, int n_in,
                              void* d_out, int out_size, void* d_ws, size_t ws_size,
                              hipStream_t stream) {
  (void)in_sizes; (void)n_in; (void)out_size;
  const float* Q = (const float*)d_in[0];
  const float* K = (const float*)d_in[1];
  const float* V = (const float*)d_in[2];
  float* Out = (float*)d_out;

  if (ws_size >= WS_NEEDED) {
    ushort4* Khi = (ushort4*)d_ws;
    ushort4* Klo = (ushort4*)((char*)d_ws + 8388608u * 2u);
    convert_k<<<dim3(8192), 256, 0, stream>>>((const float4*)K, Khi, Klo);

    (void)hipFuncSetAttribute(reinterpret_cast<const void*>(&topk_attn_mfma),
                              hipFuncAttributeMaxDynamicSharedMemorySize, LDS_BYTES);
    topk_attn_mfma<<<dim3(8192), NTHREADS, LDS_BYTES, stream>>>(
        Q, V, (const unsigned short*)Khi, (const unsigned short*)Klo, Out);
  } else {
    (void)hipFuncSetAttribute(reinterpret_cast<const void*>(&topk_attn_fb),
                              hipFuncAttributeMaxDynamicSharedMemorySize, FB_LDS_BYTES);
    topk_attn_fb<<<dim3(16384), NTHREADS, FB_LDS_BYTES, stream>>>(Q, K, V, Out);
  }
}